// Round 9
// baseline (100.876 us; speedup 1.0000x reference)
//
#include <hip/hip_runtime.h>
#include <hip/hip_fp16.h>

#define B_SZ 4096
#define T_SZ 200
#define IN_SZ 34
#define WT_FLOATS 560               // 34*16 transposed W + 16 bias
#define XG_THREADS 204800           // 800 blocks * 256 thr, 4 rows each
// HIDDEN = 4, 4*H = 16 gates, gate order i,f,g,o (rows of W_ih/W_hh)
// xg layout: [b][j][t][i,f,g,o] fp16  (lane-contiguous streams for the scan)

typedef __attribute__((ext_vector_type(2))) float f32x2;

__device__ __forceinline__ float sigf(float x) {
    return 1.0f / (1.0f + __expf(-x));
}
__device__ __forceinline__ float tanh_f(float x) {
    return 2.0f / (1.0f + __expf(-2.0f * x)) - 1.0f;
}

// broadcast lane L (0..3) of each quad to all 4 lanes of the quad via DPP
__device__ __forceinline__ float quad_bcast0(float v) {
    int s = __float_as_int(v);
    return __int_as_float(__builtin_amdgcn_update_dpp(s, s, 0x00, 0xf, 0xf, true));
}
__device__ __forceinline__ float quad_bcast1(float v) {
    int s = __float_as_int(v);
    return __int_as_float(__builtin_amdgcn_update_dpp(s, s, 0x55, 0xf, 0xf, true));
}
__device__ __forceinline__ float quad_bcast2(float v) {
    int s = __float_as_int(v);
    return __int_as_float(__builtin_amdgcn_update_dpp(s, s, 0xAA, 0xf, 0xf, true));
}
__device__ __forceinline__ float quad_bcast3(float v) {
    int s = __float_as_int(v);
    return __int_as_float(__builtin_amdgcn_update_dpp(s, s, 0xFF, 0xf, 0xf, true));
}

// Prep: Wt[k*16+g] = W_ih[g*34+k] (contiguous 16-gate rows -> wide s_loads),
// Wt[544+g] = b_ih[g]+b_hh[g]. Tiny, runs once per call.
__global__ __launch_bounds__(64) void prep_kernel(
    const float* __restrict__ W_ih, const float* __restrict__ b_ih,
    const float* __restrict__ b_hh, float* __restrict__ wt) {
  for (int i = threadIdx.x; i < WT_FLOATS; i += 64) {
    if (i < 544) {
      int k = i >> 4, g = i & 15;
      wt[i] = W_ih[g * IN_SZ + k];
    } else {
      wt[i] = b_ih[i - 544] + b_hh[i - 544];
    }
  }
}

#define WAITV(n_)                                                              \
  do {                                                                         \
    asm volatile("s_waitcnt vmcnt(" #n_ ")" ::: "memory");                     \
    __builtin_amdgcn_sched_barrier(0);                                         \
  } while (0)

// ---- Phase 1: gates (fp16) = x @ W^T + bias -> [b][j][t][ifgo] ----
// Direct per-lane row loads (no LDS): 17 asm dwordx2 into NAMED f32x2 regs,
// 1-row-ahead ping-pong, counted vmcnt. 4 rows/thread. Wave's 17 loads touch
// one contiguous 8.7KB span -> L1 line reuse; transposed wt -> wide s_loads.
#define ISSUE17(P, r)                                                          \
  asm volatile("global_load_dwordx2 %0, %[p], off\n\t"                         \
               "global_load_dwordx2 %1, %[p], off offset:8\n\t"                \
               "global_load_dwordx2 %2, %[p], off offset:16\n\t"               \
               "global_load_dwordx2 %3, %[p], off offset:24\n\t"               \
               "global_load_dwordx2 %4, %[p], off offset:32\n\t"               \
               "global_load_dwordx2 %5, %[p], off offset:40\n\t"               \
               "global_load_dwordx2 %6, %[p], off offset:48\n\t"               \
               "global_load_dwordx2 %7, %[p], off offset:56\n\t"               \
               "global_load_dwordx2 %8, %[p], off offset:64\n\t"               \
               "global_load_dwordx2 %9, %[p], off offset:72\n\t"               \
               "global_load_dwordx2 %10, %[p], off offset:80\n\t"              \
               "global_load_dwordx2 %11, %[p], off offset:88\n\t"              \
               "global_load_dwordx2 %12, %[p], off offset:96\n\t"              \
               "global_load_dwordx2 %13, %[p], off offset:104\n\t"             \
               "global_load_dwordx2 %14, %[p], off offset:112\n\t"             \
               "global_load_dwordx2 %15, %[p], off offset:120\n\t"             \
               "global_load_dwordx2 %16, %[p], off offset:128"                 \
               : "=&v"(r##0), "=&v"(r##1), "=&v"(r##2), "=&v"(r##3),           \
                 "=&v"(r##4), "=&v"(r##5), "=&v"(r##6), "=&v"(r##7),           \
                 "=&v"(r##8), "=&v"(r##9), "=&v"(r##10), "=&v"(r##11),         \
                 "=&v"(r##12), "=&v"(r##13), "=&v"(r##14), "=&v"(r##15),       \
                 "=&v"(r##16)                                                  \
               : [p] "v"(P))

#define FMA2(vv, kk)                                                           \
  do {                                                                         \
    _Pragma("unroll") for (int g = 0; g < 16; ++g)                             \
        acc[g] = fmaf((vv).x, wt[(2 * (kk)) * 16 + g], acc[g]);                \
    _Pragma("unroll") for (int g = 0; g < 16; ++g)                             \
        acc[g] = fmaf((vv).y, wt[(2 * (kk) + 1) * 16 + g], acc[g]);            \
  } while (0)

#define ROWCOMP(r)                                                             \
  do {                                                                         \
    FMA2(r##0, 0); FMA2(r##1, 1); FMA2(r##2, 2); FMA2(r##3, 3);                \
    FMA2(r##4, 4); FMA2(r##5, 5); FMA2(r##6, 6); FMA2(r##7, 7);                \
    FMA2(r##8, 8); FMA2(r##9, 9); FMA2(r##10, 10); FMA2(r##11, 11);            \
    FMA2(r##12, 12); FMA2(r##13, 13); FMA2(r##14, 14); FMA2(r##15, 15);        \
    _Pragma("unroll") for (int g = 0; g < 16; ++g)                             \
        acc[g] = fmaf((r##16).x, wt[32 * 16 + g], acc[g]);                     \
    _Pragma("unroll") for (int g = 0; g < 16; ++g)                             \
        acc[g] = fmaf((r##16).y, wt[33 * 16 + g], acc[g]);                     \
  } while (0)

__global__ __launch_bounds__(256, 1) void xgates_kernel(
    const float* __restrict__ x, const float* __restrict__ wt,
    __half* __restrict__ xg) {
  const unsigned g0 = blockIdx.x * 256 + threadIdx.x;  // row for q=0

  float bias[16];
  #pragma unroll
  for (int gg = 0; gg < 16; ++gg) bias[gg] = wt[544 + gg];

  f32x2 A0, A1, A2, A3, A4, A5, A6, A7, A8, A9, A10, A11, A12, A13, A14, A15, A16;
  f32x2 B0, B1, B2, B3, B4, B5, B6, B7, B8, B9, B10, B11, B12, B13, B14, B15, B16;

  const char* xb = reinterpret_cast<const char*>(x);
  uint2* xg2 = reinterpret_cast<uint2*>(xg);

  auto rowaddr = [&](int q) {
    return xb + (size_t)(g0 + (unsigned)q * XG_THREADS) * 136;
  };
  auto store_gates = [&](int q, const float* acc) {
    unsigned r = g0 + (unsigned)q * XG_THREADS;
    unsigned bb = r / 200u;
    unsigned tt = r - bb * 200u;
    size_t base = (size_t)bb * 800u + tt;  // + j*200
    #pragma unroll
    for (int j = 0; j < 4; ++j) {
      union { __half2 h[2]; uint2 v; } u;
      u.h[0] = __floats2half2_rn(acc[0 + j], acc[4 + j]);
      u.h[1] = __floats2half2_rn(acc[8 + j], acc[12 + j]);
      xg2[base + (size_t)j * 200u] = u.v;  // 4 global_store_dwordx2 (vmcnt)
    }
  };

  float acc[16];

  ISSUE17(rowaddr(0), A);
  // q0: issue row1, wait A (out: A17,B17 -> vmcnt(17))
  ISSUE17(rowaddr(1), B);
  WAITV(17);
  #pragma unroll
  for (int gg = 0; gg < 16; ++gg) acc[gg] = bias[gg];
  ROWCOMP(A);
  store_gates(0, acc);
  // q1: issue row2 into A, wait B (out: B17,S0(4),A17 -> vmcnt(21))
  ISSUE17(rowaddr(2), A);
  WAITV(21);
  #pragma unroll
  for (int gg = 0; gg < 16; ++gg) acc[gg] = bias[gg];
  ROWCOMP(B);
  store_gates(1, acc);
  // q2: issue row3 into B, wait A (out: A17,S1,B17 -> vmcnt(21))
  ISSUE17(rowaddr(3), B);
  WAITV(21);
  #pragma unroll
  for (int gg = 0; gg < 16; ++gg) acc[gg] = bias[gg];
  ROWCOMP(A);
  store_gates(2, acc);
  // q3: wait B (out: B17,S2(4) -> vmcnt(4))
  WAITV(4);
  #pragma unroll
  for (int gg = 0; gg < 16; ++gg) acc[gg] = bias[gg];
  ROWCOMP(B);
  store_gates(3, acc);
}

// ---- Phase 2: recurrent scan ----
// 4 lanes per batch element, lane j owns h_j/c_j. Lane stream contiguous
// (1600B). Named-SSA asm loads + counted vmcnt ping-pong. launch_bounds
// (64,1) lifts the default 64-VGPR occupancy cap so the 2x10 uint4 buffers
// actually get registers (R8: cap caused full scratch spill).
#define ISSUE10(P, r)                                                          \
  asm volatile("global_load_dwordx4 %0, %[p], off\n\t"                         \
               "global_load_dwordx4 %1, %[p], off offset:16\n\t"               \
               "global_load_dwordx4 %2, %[p], off offset:32\n\t"               \
               "global_load_dwordx4 %3, %[p], off offset:48\n\t"               \
               "global_load_dwordx4 %4, %[p], off offset:64\n\t"               \
               "global_load_dwordx4 %5, %[p], off offset:80\n\t"               \
               "global_load_dwordx4 %6, %[p], off offset:96\n\t"               \
               "global_load_dwordx4 %7, %[p], off offset:112\n\t"              \
               "global_load_dwordx4 %8, %[p], off offset:128\n\t"              \
               "global_load_dwordx4 %9, %[p], off offset:144"                  \
               : "=&v"(r##0), "=&v"(r##1), "=&v"(r##2), "=&v"(r##3),           \
                 "=&v"(r##4), "=&v"(r##5), "=&v"(r##6), "=&v"(r##7),           \
                 "=&v"(r##8), "=&v"(r##9)                                      \
               : [p] "v"(P))

#define STEP4(v)                                                               \
  step((v).x, (v).y);                                                          \
  step((v).z, (v).w)
#define STEPS(r)                                                               \
  STEP4(r##0); STEP4(r##1); STEP4(r##2); STEP4(r##3); STEP4(r##4);             \
  STEP4(r##5); STEP4(r##6); STEP4(r##7); STEP4(r##8); STEP4(r##9)

__global__ __launch_bounds__(64, 1) void lstm_scan(
    const __half* __restrict__ xg, const float* __restrict__ W_hh,
    const float* __restrict__ W_fc, const float* __restrict__ b_fc,
    float* __restrict__ out) {
  int tid = blockIdx.x * 64 + threadIdx.x;
  int b = tid >> 2;
  int j = tid & 3;
  float Wi[4], Wf[4], Wg[4], Wo[4];
  #pragma unroll
  for (int k = 0; k < 4; ++k) {
    Wi[k] = W_hh[(0 + j) * 4 + k];
    Wf[k] = W_hh[(4 + j) * 4 + k];
    Wg[k] = W_hh[(8 + j) * 4 + k];
    Wo[k] = W_hh[(12 + j) * 4 + k];
  }
  float h[4] = {0.f, 0.f, 0.f, 0.f};
  float c = 0.f;

  auto step = [&](unsigned lo, unsigned hi) {
    union { unsigned u; __half2 h2; } a_, b_;
    a_.u = lo;
    b_.u = hi;
    float2 p01 = __half22float2(a_.h2);  // (i, f)
    float2 p23 = __half22float2(b_.h2);  // (g, o)
    float pi = p01.x, pf = p01.y, pg = p23.x, po = p23.y;
    #pragma unroll
    for (int k = 0; k < 4; ++k) {
      pi = fmaf(Wi[k], h[k], pi);
      pf = fmaf(Wf[k], h[k], pf);
      pg = fmaf(Wg[k], h[k], pg);
      po = fmaf(Wo[k], h[k], po);
    }
    float iv = sigf(pi);
    float fv = sigf(pf);
    float gv = tanh_f(pg);
    float ov = sigf(po);
    c = fmaf(fv, c, iv * gv);
    float hj = ov * tanh_f(c);
    h[0] = quad_bcast0(hj);
    h[1] = quad_bcast1(hj);
    h[2] = quad_bcast2(hj);
    h[3] = quad_bcast3(hj);
  };

  // lane stream base: b*6400 + j*1600 bytes; batch = 10 dwordx4 = 20 steps
  const char* base = reinterpret_cast<const char*>(xg) +
                     (size_t)b * 6400 + (size_t)j * 1600;
  uint4 a0, a1, a2, a3, a4, a5, a6, a7, a8, a9;
  uint4 b0, b1, b2, b3, b4, b5, b6, b7, b8, b9;

  ISSUE10(base, a);         // batch 0
  ISSUE10(base + 160, b);   // batch 1
  const char* pa = base + 320;
  const char* pb = base + 480;

  #pragma unroll 1
  for (int it = 0; it < 4; ++it) {
    WAITV(10);              // FIFO: drains current a batch, keeps b's 10
    STEPS(a);
    ISSUE10(pa, a);
    pa += 320;
    WAITV(10);              // drains b batch, keeps new a's 10
    STEPS(b);
    ISSUE10(pb, b);
    pb += 320;
  }
  WAITV(10);                // drain batch 8
  STEPS(a);
  WAITV(0);                 // drain batch 9
  STEPS(b);

  if (j < 3) {
    float acc = b_fc[j];
    #pragma unroll
    for (int k = 0; k < 4; ++k) acc = fmaf(W_fc[j * 4 + k], h[k], acc);
    out[b * 3 + j] = acc;
  }
}

// Fallback (only if workspace is too small): fused single kernel, W_ih in LDS.
__global__ __launch_bounds__(256) void lstm_fused(
    const float* __restrict__ x, const float* __restrict__ W_ih,
    const float* __restrict__ W_hh, const float* __restrict__ b_ih,
    const float* __restrict__ b_hh, const float* __restrict__ W_fc,
    const float* __restrict__ b_fc, float* __restrict__ out) {
  __shared__ float Ws[16 * IN_SZ];
  for (int i = threadIdx.x; i < 16 * IN_SZ; i += 256) Ws[i] = W_ih[i];
  __syncthreads();
  int tid = blockIdx.x * 256 + threadIdx.x;
  int b = tid >> 2;
  int j = tid & 3;
  float bi = b_ih[0 + j] + b_hh[0 + j];
  float bf = b_ih[4 + j] + b_hh[4 + j];
  float bg = b_ih[8 + j] + b_hh[8 + j];
  float bo = b_ih[12 + j] + b_hh[12 + j];
  float Wi[4], Wf[4], Wg[4], Wo[4];
  #pragma unroll
  for (int k = 0; k < 4; ++k) {
    Wi[k] = W_hh[(0 + j) * 4 + k];
    Wf[k] = W_hh[(4 + j) * 4 + k];
    Wg[k] = W_hh[(8 + j) * 4 + k];
    Wo[k] = W_hh[(12 + j) * 4 + k];
  }
  float h[4] = {0.f, 0.f, 0.f, 0.f};
  float c = 0.f;
  const float2* xp = reinterpret_cast<const float2*>(x + (size_t)b * T_SZ * IN_SZ);
  int lbase = (threadIdx.x & 63) & ~3;
  for (int t = 0; t < T_SZ; ++t) {
    float xr[IN_SZ];
    #pragma unroll
    for (int k = 0; k < IN_SZ / 2; ++k) {
      float2 v = xp[(size_t)t * (IN_SZ / 2) + k];
      xr[2 * k] = v.x;
      xr[2 * k + 1] = v.y;
    }
    float pi = bi, pf = bf, pg = bg, po = bo;
    #pragma unroll
    for (int k = 0; k < IN_SZ; ++k) {
      pi = fmaf(xr[k], Ws[(0 + j) * IN_SZ + k], pi);
      pf = fmaf(xr[k], Ws[(4 + j) * IN_SZ + k], pf);
      pg = fmaf(xr[k], Ws[(8 + j) * IN_SZ + k], pg);
      po = fmaf(xr[k], Ws[(12 + j) * IN_SZ + k], po);
    }
    #pragma unroll
    for (int k = 0; k < 4; ++k) {
      pi = fmaf(Wi[k], h[k], pi);
      pf = fmaf(Wf[k], h[k], pf);
      pg = fmaf(Wg[k], h[k], pg);
      po = fmaf(Wo[k], h[k], po);
    }
    float iv = sigf(pi);
    float fv = sigf(pf);
    float gv = tanh_f(pg);
    float ov = sigf(po);
    c = fmaf(fv, c, iv * gv);
    float hj = ov * tanh_f(c);
    h[0] = __shfl(hj, lbase + 0);
    h[1] = __shfl(hj, lbase + 1);
    h[2] = __shfl(hj, lbase + 2);
    h[3] = __shfl(hj, lbase + 3);
  }
  if (j < 3) {
    float acc = b_fc[j];
    #pragma unroll
    for (int k = 0; k < 4; ++k) acc = fmaf(W_fc[j * 4 + k], h[k], acc);
    out[b * 3 + j] = acc;
  }
}

extern "C" void kernel_launch(void* const* d_in, const int* in_sizes, int n_in,
                              void* d_out, int out_size, void* d_ws, size_t ws_size,
                              hipStream_t stream) {
  const float* x    = (const float*)d_in[0];
  const float* W_ih = (const float*)d_in[1];
  const float* W_hh = (const float*)d_in[2];
  const float* b_ih = (const float*)d_in[3];
  const float* b_hh = (const float*)d_in[4];
  const float* W_fc = (const float*)d_in[5];
  const float* b_fc = (const float*)d_in[6];
  float* out = (float*)d_out;

  const size_t xg_off = 4096;  // Wt table lives at ws[0..2240)
  const size_t need = xg_off + (size_t)B_SZ * T_SZ * 16 * sizeof(__half);
  if (ws_size >= need) {
    float* wt = (float*)d_ws;
    __half* xg = (__half*)((char*)d_ws + xg_off);
    hipLaunchKernelGGL(prep_kernel, dim3(1), dim3(64), 0, stream,
                       W_ih, b_ih, b_hh, wt);
    hipLaunchKernelGGL(xgates_kernel, dim3(XG_THREADS / 256), dim3(256), 0, stream,
                       x, wt, xg);
    hipLaunchKernelGGL(lstm_scan, dim3(B_SZ * 4 / 64), dim3(64), 0, stream,
                       xg, W_hh, W_fc, b_fc, out);
  } else {
    hipLaunchKernelGGL(lstm_fused, dim3(B_SZ * 4 / 256), dim3(256), 0, stream,
                       x, W_ih, W_hh, b_ih, b_hh, W_fc, b_fc, out);
  }
}